// Round 2
// baseline (761.582 us; speedup 1.0000x reference)
//
#include <hip/hip_runtime.h>
#include <hip/hip_bf16.h>

#define S_LEN 2048
#define H_DIM 2048
#define NHEADS 16
#define KVHEADS 4
#define HEAD_DIM 128
#define KV_DIM 512       // KVHEADS * HEAD_DIM
#define NTOK 4096        // B * S

typedef __bf16 bf16_t;
typedef __bf16 bf16x8 __attribute__((ext_vector_type(8)));
typedef float f32x4 __attribute__((ext_vector_type(4)));

__device__ __forceinline__ f32x4 mfma16x16x32(bf16x8 a, bf16x8 b, f32x4 c) {
    return __builtin_amdgcn_mfma_f32_16x16x32_bf16(a, b, c, 0, 0, 0);
}

// fp32 -> bf16 bulk convert; n must be a multiple of 8.
__global__ __launch_bounds__(256) void cvt_f32_bf16(const float* __restrict__ src,
                                                    bf16_t* __restrict__ dst, int n) {
    const int i = (blockIdx.x * 256 + threadIdx.x) * 8;
    if (i >= n) return;
    const float4 a = *(const float4*)(src + i);
    const float4 b = *(const float4*)(src + i + 4);
    bf16x8 o;
    o[0] = (bf16_t)a.x; o[1] = (bf16_t)a.y; o[2] = (bf16_t)a.z; o[3] = (bf16_t)a.w;
    o[4] = (bf16_t)b.x; o[5] = (bf16_t)b.y; o[6] = (bf16_t)b.z; o[7] = (bf16_t)b.w;
    *(bf16x8*)(dst + i) = o;
}

// C[m][n] = sum_k A[m][k] * W[n][k].  A: MxK bf16 row-major, W: NxK bf16
// row-major, C: MxN OutT row-major. Block = 256 thr = 4 waves (2x2); wave
// tile 64x64. Layouts (HW-verified): A-op m=lane&15,k=quad*8+j; B-op
// n=lane&15,k=quad*8+j; C/D row=quad*4+r, col=lane&15.
template <typename OutT>
__global__ __launch_bounds__(256) void gemm_bt(const bf16_t* __restrict__ A,
                                               const bf16_t* __restrict__ W,
                                               OutT* __restrict__ C,
                                               int M, int N, int K) {
    const int wave = threadIdx.x >> 6;
    const int lane = threadIdx.x & 63;
    const int col  = lane & 15;
    const int quad = lane >> 4;
    const int m0 = blockIdx.y * 128 + (wave >> 1) * 64;
    const int n0 = blockIdx.x * 128 + (wave & 1) * 64;

    const bf16_t* ap[4];
    const bf16_t* bp[4];
#pragma unroll
    for (int i = 0; i < 4; ++i) {
        ap[i] = A + (size_t)(m0 + i * 16 + col) * K + quad * 8;
        bp[i] = W + (size_t)(n0 + i * 16 + col) * K + quad * 8;
    }
    f32x4 acc[4][4];
#pragma unroll
    for (int mi = 0; mi < 4; ++mi)
#pragma unroll
        for (int ni = 0; ni < 4; ++ni)
            acc[mi][ni] = (f32x4){0.f, 0.f, 0.f, 0.f};

    for (int k0 = 0; k0 < K; k0 += 32) {
        bf16x8 av[4], bv[4];
#pragma unroll
        for (int i = 0; i < 4; ++i) {
            av[i] = *(const bf16x8*)(ap[i] + k0);
            bv[i] = *(const bf16x8*)(bp[i] + k0);
        }
#pragma unroll
        for (int mi = 0; mi < 4; ++mi)
#pragma unroll
            for (int ni = 0; ni < 4; ++ni)
                acc[mi][ni] = mfma16x16x32(av[mi], bv[ni], acc[mi][ni]);
    }
#pragma unroll
    for (int mi = 0; mi < 4; ++mi)
#pragma unroll
        for (int ni = 0; ni < 4; ++ni)
#pragma unroll
            for (int r = 0; r < 4; ++r)
                C[(size_t)(m0 + mi * 16 + quad * 4 + r) * N + n0 + ni * 16 + col] =
                    (OutT)acc[mi][ni][r];
}

// In-place RoPE on Q [NTOK][2048] (16 heads) and K [NTOK][512] (4 heads),
// bf16 data, fp32 cos/sin tables. One thread per (row, head, d<64).
__global__ __launch_bounds__(256) void rope_inplace(bf16_t* __restrict__ Qb,
                                                    bf16_t* __restrict__ Kb,
                                                    const float* __restrict__ cosb,
                                                    const float* __restrict__ sinb) {
    const int idx  = blockIdx.x * 256 + threadIdx.x;   // NTOK*20*64 total
    const int d    = idx & 63;
    const int rem  = idx >> 6;
    const int head = rem % 20;
    const int row  = rem / 20;
    if (row >= NTOK) return;
    const int s = row & (S_LEN - 1);
    const float c0 = cosb[s * HEAD_DIM + d];
    const float s0 = sinb[s * HEAD_DIM + d];
    const float c1 = cosb[s * HEAD_DIM + 64 + d];
    const float s1 = sinb[s * HEAD_DIM + 64 + d];
    bf16_t* base = (head < NHEADS)
        ? Qb + (size_t)row * H_DIM + head * HEAD_DIM
        : Kb + (size_t)row * KV_DIM + (head - NHEADS) * HEAD_DIM;
    const float lo = (float)base[d];
    const float hi = (float)base[d + 64];
    base[d]      = (bf16_t)(lo * c0 - hi * s0);   // x_lo*cos - x_hi*sin
    base[d + 64] = (bf16_t)(hi * c1 + lo * s1);   // x_hi*cos + x_lo*sin
}

#define NEG_BIG (-1e30f)

// Flash attention with causal mask. Block = (b, kvh, 16-row q tile); the 4
// waves are the 4 GQA heads sharing this kv head's K/V. kv steps of 32.
// O is written IN PLACE into the Q buffer (each 16x128 region is read only
// by the wave that later writes it; read precedes write in program order).
__global__ __launch_bounds__(256) void attn_fwd(bf16_t* __restrict__ Q,
                                                const bf16_t* __restrict__ Kb,
                                                const bf16_t* __restrict__ Vb) {
    const int qt  = blockIdx.x;        // 0..127
    const int kvh = blockIdx.y;        // 0..3
    const int b   = blockIdx.z;        // 0..1
    const int q0  = qt * 16;
    const int wave = threadIdx.x >> 6; // head-in-group
    const int lane = threadIdx.x & 63;
    const int col  = lane & 15;
    const int quad = lane >> 4;
    const int h = kvh * 4 + wave;

    // pad rows to 40 elems (80B): 16B-aligned ds_read_b128, ~2-way banks (free)
    __shared__ alignas(16) bf16_t Vt[HEAD_DIM][40];  // V tile transposed
    __shared__ alignas(16) bf16_t Pb[4][16][40];     // per-wave P round-trip

    bf16x8 aQ[4];
    {
        const bf16_t* qp = Q + (size_t)(b * S_LEN + q0 + col) * H_DIM + h * HEAD_DIM + quad * 8;
#pragma unroll
        for (int t = 0; t < 4; ++t) aQ[t] = *(const bf16x8*)(qp + t * 32);
    }
    const bf16_t* kbase = Kb + (size_t)(b * S_LEN) * KV_DIM + kvh * HEAD_DIM;
    const bf16_t* vbase = Vb + (size_t)(b * S_LEN) * KV_DIM + kvh * HEAD_DIM;

    f32x4 Oacc[8];
#pragma unroll
    for (int dt = 0; dt < 8; ++dt) Oacc[dt] = (f32x4){0.f, 0.f, 0.f, 0.f};
    float m_i[4], l_i[4];
#pragma unroll
    for (int r = 0; r < 4; ++r) { m_i[r] = NEG_BIG; l_i[r] = 0.f; }

    const float scale = 0.08838834764831845f;  // 1/sqrt(128)
    const int nsteps = (q0 + 15) / 32 + 1;

    for (int jt = 0; jt < nsteps; ++jt) {
        const int j0 = jt * 32;
        __syncthreads();   // protect Vt reuse from previous step
        {  // stage V[j0..j0+31][.] transposed into Vt (coalesced global read)
            const int t = threadIdx.x;
            const int jj = t >> 3;            // 0..31
            const int dbase = (t & 7) * 16;   // 0..112
            const bf16_t* vp = vbase + (size_t)(j0 + jj) * KV_DIM + dbase;
            bf16x8 v0 = *(const bf16x8*)vp;
            bf16x8 v1 = *(const bf16x8*)(vp + 8);
#pragma unroll
            for (int e = 0; e < 8; ++e) {
                Vt[dbase + e][jj]     = v0[e];
                Vt[dbase + 8 + e][jj] = v1[e];
            }
        }
        __syncthreads();

        // S(16x32) = Q(16x128) . K^T ; K rows load contiguous as B-operand
        f32x4 sc[2];
        sc[0] = (f32x4){0.f, 0.f, 0.f, 0.f};
        sc[1] = (f32x4){0.f, 0.f, 0.f, 0.f};
#pragma unroll
        for (int jc = 0; jc < 2; ++jc) {
            const bf16_t* kp = kbase + (size_t)(j0 + jc * 16 + col) * KV_DIM + quad * 8;
#pragma unroll
            for (int t = 0; t < 4; ++t) {
                bf16x8 bK = *(const bf16x8*)(kp + t * 32);
                sc[jc] = mfma16x16x32(aQ[t], bK, sc[jc]);
            }
        }
        // scale + causal mask (q row = q0 + quad*4 + r, kv col = j0 + jc*16 + col)
        const int qrow = q0 + quad * 4;
#pragma unroll
        for (int jc = 0; jc < 2; ++jc) {
            const int j = j0 + jc * 16 + col;
#pragma unroll
            for (int r = 0; r < 4; ++r) {
                float s = sc[jc][r] * scale;
                sc[jc][r] = (j <= qrow + r) ? s : NEG_BIG;
            }
        }
        // online softmax: row reductions across the quad's 16 lanes
        float alpha[4];
#pragma unroll
        for (int r = 0; r < 4; ++r) {
            float v = fmaxf(sc[0][r], sc[1][r]);
            v = fmaxf(v, __shfl_xor(v, 1, 16));
            v = fmaxf(v, __shfl_xor(v, 2, 16));
            v = fmaxf(v, __shfl_xor(v, 4, 16));
            v = fmaxf(v, __shfl_xor(v, 8, 16));
            float mn = fmaxf(m_i[r], v);      // finite after first step
            alpha[r] = __expf(m_i[r] - mn);   // first step: exp(~-1e30) = 0
            m_i[r] = mn;
        }
#pragma unroll
        for (int r = 0; r < 4; ++r) {
            float p0 = __expf(sc[0][r] - m_i[r]);   // masked -> underflow to 0
            float p1 = __expf(sc[1][r] - m_i[r]);
            sc[0][r] = p0; sc[1][r] = p1;
            float v = p0 + p1;
            v += __shfl_xor(v, 1, 16);
            v += __shfl_xor(v, 2, 16);
            v += __shfl_xor(v, 4, 16);
            v += __shfl_xor(v, 8, 16);
            l_i[r] = l_i[r] * alpha[r] + v;
        }
#pragma unroll
        for (int dt = 0; dt < 8; ++dt)
#pragma unroll
            for (int r = 0; r < 4; ++r) Oacc[dt][r] *= alpha[r];

        // P: C-layout -> LDS -> A-layout (verified m120 recipe); same-wave only
#pragma unroll
        for (int jc = 0; jc < 2; ++jc)
#pragma unroll
            for (int r = 0; r < 4; ++r)
                Pb[wave][quad * 4 + r][jc * 16 + col] = (bf16_t)sc[jc][r];
        asm volatile("s_waitcnt lgkmcnt(0)" ::: "memory");
        bf16x8 aP = *(const bf16x8*)(&Pb[wave][col][quad * 8]);
#pragma unroll
        for (int dt = 0; dt < 8; ++dt) {
            bf16x8 bV = *(const bf16x8*)(&Vt[dt * 16 + col][quad * 8]);
            Oacc[dt] = mfma16x16x32(aP, bV, Oacc[dt]);
        }
    }

    // normalize and store IN PLACE over this wave's own Q region
#pragma unroll
    for (int r = 0; r < 4; ++r) {
        const float inv = 1.0f / l_i[r];
        const size_t rowoff = (size_t)(b * S_LEN + q0 + quad * 4 + r) * H_DIM + h * HEAD_DIM;
#pragma unroll
        for (int dt = 0; dt < 8; ++dt)
            Q[rowoff + dt * 16 + col] = (bf16_t)(Oacc[dt][r] * inv);
    }
}

extern "C" void kernel_launch(void* const* d_in, const int* in_sizes, int n_in,
                              void* d_out, int out_size, void* d_ws, size_t ws_size,
                              hipStream_t stream) {
    const float* X    = (const float*)d_in[0];
    const float* cosb = (const float*)d_in[1];
    const float* sinb = (const float*)d_in[2];
    const float* Wq   = (const float*)d_in[3];
    const float* Wk   = (const float*)d_in[4];
    const float* Wv   = (const float*)d_in[5];
    const float* Wo   = (const float*)d_in[6];
    float* out = (float*)d_out;

    // ws layout (all bf16): Xb 16MB | Wqb 8MB | Wkb 2MB | Wvb 2MB | Wob 8MB |
    //                       Q 16MB | K 4MB | V 4MB          (total 60MB)
    char* ws = (char*)d_ws;
    bf16_t* Xb  = (bf16_t*)(ws);
    bf16_t* Wqb = (bf16_t*)(ws + (16u << 20));
    bf16_t* Wkb = (bf16_t*)(ws + (24u << 20));
    bf16_t* Wvb = (bf16_t*)(ws + (26u << 20));
    bf16_t* Wob = (bf16_t*)(ws + (28u << 20));
    bf16_t* qbuf = (bf16_t*)(ws + (36u << 20));
    bf16_t* kbuf = (bf16_t*)(ws + (52u << 20));
    bf16_t* vbuf = (bf16_t*)(ws + (56u << 20));

    dim3 blk(256, 1, 1);
    const int nX = NTOK * H_DIM, nWq = H_DIM * H_DIM, nWk = KV_DIM * H_DIM;
    cvt_f32_bf16<<<dim3(nX / 2048, 1, 1), blk, 0, stream>>>(X, Xb, nX);
    cvt_f32_bf16<<<dim3(nWq / 2048, 1, 1), blk, 0, stream>>>(Wq, Wqb, nWq);
    cvt_f32_bf16<<<dim3(nWk / 2048, 1, 1), blk, 0, stream>>>(Wk, Wkb, nWk);
    cvt_f32_bf16<<<dim3(nWk / 2048, 1, 1), blk, 0, stream>>>(Wv, Wvb, nWk);
    cvt_f32_bf16<<<dim3(nWq / 2048, 1, 1), blk, 0, stream>>>(Wo, Wob, nWq);

    gemm_bt<bf16_t><<<dim3(H_DIM / 128, NTOK / 128, 1), blk, 0, stream>>>(Xb, Wqb, qbuf, NTOK, H_DIM, H_DIM);
    gemm_bt<bf16_t><<<dim3(KV_DIM / 128, NTOK / 128, 1), blk, 0, stream>>>(Xb, Wkb, kbuf, NTOK, KV_DIM, H_DIM);
    gemm_bt<bf16_t><<<dim3(KV_DIM / 128, NTOK / 128, 1), blk, 0, stream>>>(Xb, Wvb, vbuf, NTOK, KV_DIM, H_DIM);
    rope_inplace<<<dim3((NTOK * 20 * 64) / 256, 1, 1), blk, 0, stream>>>(qbuf, kbuf, cosb, sinb);
    attn_fwd<<<dim3(S_LEN / 16, KVHEADS, 2), blk, 0, stream>>>(qbuf, kbuf, vbuf);
    gemm_bt<float><<<dim3(H_DIM / 128, NTOK / 128, 1), blk, 0, stream>>>(qbuf, Wob, out, NTOK, H_DIM, H_DIM);

    (void)in_sizes; (void)n_in; (void)out_size; (void)ws_size;
}

// Round 3
// 613.659 us; speedup vs baseline: 1.2411x; 1.2411x over previous
//
#include <hip/hip_runtime.h>
#include <hip/hip_bf16.h>
#include <stdint.h>

#define S_LEN 2048
#define H_DIM 2048
#define NHEADS 16
#define KVHEADS 4
#define HEAD_DIM 128
#define KV_DIM 512       // KVHEADS * HEAD_DIM
#define NTOK 4096        // B * S

typedef __bf16 bf16_t;
typedef __bf16 bf16x8 __attribute__((ext_vector_type(8)));
typedef __bf16 bf16x4 __attribute__((ext_vector_type(4)));
typedef float f32x4 __attribute__((ext_vector_type(4)));

__device__ __forceinline__ f32x4 mfma16x16x32(bf16x8 a, bf16x8 b, f32x4 c) {
    return __builtin_amdgcn_mfma_f32_16x16x32_bf16(a, b, c, 0, 0, 0);
}

// async global->LDS, 16B per lane. LDS dest is wave-uniform base + lane*16.
__device__ __forceinline__ void gload_lds16(const bf16_t* g, bf16_t* l) {
    __builtin_amdgcn_global_load_lds(
        (__attribute__((address_space(1))) uint32_t*)(uintptr_t)g,
        (__attribute__((address_space(3))) uint32_t*)l, 16, 0, 0);
}

// fp32 -> bf16 bulk convert; n must be a multiple of 8.
__global__ __launch_bounds__(256) void cvt_f32_bf16(const float* __restrict__ src,
                                                    bf16_t* __restrict__ dst, int n) {
    const int i = (blockIdx.x * 256 + threadIdx.x) * 8;
    if (i >= n) return;
    const float4 a = *(const float4*)(src + i);
    const float4 b = *(const float4*)(src + i + 4);
    bf16x8 o;
    o[0] = (bf16_t)a.x; o[1] = (bf16_t)a.y; o[2] = (bf16_t)a.z; o[3] = (bf16_t)a.w;
    o[4] = (bf16_t)b.x; o[5] = (bf16_t)b.y; o[6] = (bf16_t)b.z; o[7] = (bf16_t)b.w;
    *(bf16x8*)(dst + i) = o;
}

// C[m][n] = sum_k A[m][k] * W[n][k]. m97 structure: 128x128 tile, BK=32,
// global_load_lds width-16 staging, ds_read_b128 fragments, 2x2 waves of
// 64x64. TRANS=true writes C transposed into V^T layout
// [b][kvh][d][s] (offset = ((m>>11)*KV_DIM + n)*S_LEN + (m&2047)).
template <typename OutT, bool TRANS>
__global__ __launch_bounds__(256) void gemm_bt(const bf16_t* __restrict__ A,
                                               const bf16_t* __restrict__ W,
                                               OutT* __restrict__ C,
                                               int M, int N, int K) {
    __shared__ alignas(16) bf16_t As[128 * 32];   // row-major [128][32], no pad
    __shared__ alignas(16) bf16_t Bs[128 * 32];
    const int tid  = threadIdx.x;
    const int wave = tid >> 6;
    const int lane = tid & 63;
    const int col  = lane & 15;
    const int quad = lane >> 4;
    const int m0 = blockIdx.y * 128;
    const int n0 = blockIdx.x * 128;
    const int wm = (wave >> 1) * 64;
    const int wn = (wave & 1) * 64;

    // staging map: flat elem offset = (chunk*256 + tid)*8 -> row = off/32, k = off%32
    const int r0 = tid >> 2;
    const int kk = (tid & 3) * 8;
    const bf16_t* a0 = A + (size_t)(m0 + r0) * K + kk;
    const bf16_t* a1 = a0 + (size_t)64 * K;
    const bf16_t* b0 = W + (size_t)(n0 + r0) * K + kk;
    const bf16_t* b1 = b0 + (size_t)64 * K;
    bf16_t* lA0 = As + tid * 8;
    bf16_t* lA1 = As + 2048 + tid * 8;
    bf16_t* lB0 = Bs + tid * 8;
    bf16_t* lB1 = Bs + 2048 + tid * 8;

    f32x4 acc[4][4];
#pragma unroll
    for (int mi = 0; mi < 4; ++mi)
#pragma unroll
        for (int ni = 0; ni < 4; ++ni)
            acc[mi][ni] = (f32x4){0.f, 0.f, 0.f, 0.f};

    for (int k0 = 0; k0 < K; k0 += 32) {
        __syncthreads();                 // all waves done reading previous tile
        gload_lds16(a0 + k0, lA0);
        gload_lds16(a1 + k0, lA1);
        gload_lds16(b0 + k0, lB0);
        gload_lds16(b1 + k0, lB1);
        __syncthreads();                 // vmcnt(0) drain + visibility
        bf16x8 av[4], bv[4];
#pragma unroll
        for (int i = 0; i < 4; ++i) {
            av[i] = *(const bf16x8*)(As + (wm + i * 16 + col) * 32 + quad * 8);
            bv[i] = *(const bf16x8*)(Bs + (wn + i * 16 + col) * 32 + quad * 8);
        }
#pragma unroll
        for (int mi = 0; mi < 4; ++mi)
#pragma unroll
            for (int ni = 0; ni < 4; ++ni)
                acc[mi][ni] = mfma16x16x32(av[mi], bv[ni], acc[mi][ni]);
    }

    if constexpr (!TRANS) {
#pragma unroll
        for (int mi = 0; mi < 4; ++mi)
#pragma unroll
            for (int ni = 0; ni < 4; ++ni)
#pragma unroll
                for (int r = 0; r < 4; ++r)
                    C[(size_t)(m0 + wm + mi * 16 + quad * 4 + r) * N +
                      n0 + wn + ni * 16 + col] = (OutT)acc[mi][ni][r];
    } else {
        // lane holds 4 consecutive m for fixed n -> 8B vector write along s
#pragma unroll
        for (int mi = 0; mi < 4; ++mi) {
            const int m = m0 + wm + mi * 16 + quad * 4;   // m..m+3, same b
#pragma unroll
            for (int ni = 0; ni < 4; ++ni) {
                const int n = n0 + wn + ni * 16 + col;
                const size_t off =
                    ((size_t)(m >> 11) * KV_DIM + n) * S_LEN + (m & (S_LEN - 1));
                bf16x4 o;
#pragma unroll
                for (int r = 0; r < 4; ++r) o[r] = (bf16_t)acc[mi][ni][r];
                *(bf16x4*)((bf16_t*)C + off) = o;
            }
        }
    }
}

// In-place RoPE on Q [NTOK][2048] (16 heads) and K [NTOK][512] (4 heads),
// bf16 data, fp32 cos/sin tables. One thread per (row, head, d<64).
__global__ __launch_bounds__(256) void rope_inplace(bf16_t* __restrict__ Qb,
                                                    bf16_t* __restrict__ Kb,
                                                    const float* __restrict__ cosb,
                                                    const float* __restrict__ sinb) {
    const int idx  = blockIdx.x * 256 + threadIdx.x;
    const int d    = idx & 63;
    const int rem  = idx >> 6;
    const int head = rem % 20;
    const int row  = rem / 20;
    if (row >= NTOK) return;
    const int s = row & (S_LEN - 1);
    const float c0 = cosb[s * HEAD_DIM + d];
    const float s0 = sinb[s * HEAD_DIM + d];
    const float c1 = cosb[s * HEAD_DIM + 64 + d];
    const float s1 = sinb[s * HEAD_DIM + 64 + d];
    bf16_t* base = (head < NHEADS)
        ? Qb + (size_t)row * H_DIM + head * HEAD_DIM
        : Kb + (size_t)row * KV_DIM + (head - NHEADS) * HEAD_DIM;
    const float lo = (float)base[d];
    const float hi = (float)base[d + 64];
    base[d]      = (bf16_t)(lo * c0 - hi * s0);
    base[d + 64] = (bf16_t)(hi * c1 + lo * s1);
}

#define NEG_BIG (-1e30f)

// Barrier-free flash attention, causal. Block = (qtile of 32 rows, kvh, b);
// 4 waves = the 4 GQA heads sharing this kv head. kv steps of 32.
// K read direct-global (row-major), V read direct-global from V^T layout
// [b][kvh][d][s] (PV B-fragments are contiguous 16B). Only LDS use is the
// per-wave P C->A layout round-trip (no __syncthreads anywhere).
// Output written IN PLACE into Q (each region read+written by one wave only).
__global__ __launch_bounds__(256) void attn_fwd(bf16_t* __restrict__ Q,
                                                const bf16_t* __restrict__ Kb,
                                                const bf16_t* __restrict__ Vt) {
    const int qt  = (int)(gridDim.x - 1) - (int)blockIdx.x;  // big tiles first
    const int kvh = blockIdx.y;
    const int b   = blockIdx.z;
    const int q0  = qt * 32;
    const int wave = threadIdx.x >> 6;
    const int lane = threadIdx.x & 63;
    const int col  = lane & 15;
    const int quad = lane >> 4;
    const int h = kvh * 4 + wave;

    __shared__ alignas(16) bf16_t Pb[4][2][16][40];  // [wave][sub][q][j] pad40

    bf16x8 aQ[2][4];
#pragma unroll
    for (int s = 0; s < 2; ++s) {
        const bf16_t* qp = Q + (size_t)(b * S_LEN + q0 + s * 16 + col) * H_DIM +
                           h * HEAD_DIM + quad * 8;
#pragma unroll
        for (int t = 0; t < 4; ++t) aQ[s][t] = *(const bf16x8*)(qp + t * 32);
    }
    const bf16_t* kbase = Kb + (size_t)(b * S_LEN) * KV_DIM + kvh * HEAD_DIM;
    const bf16_t* vtb   = Vt + (size_t)(b * KVHEADS + kvh) * HEAD_DIM * S_LEN;

    f32x4 Oacc[2][8];
#pragma unroll
    for (int s = 0; s < 2; ++s)
#pragma unroll
        for (int dt = 0; dt < 8; ++dt) Oacc[s][dt] = (f32x4){0.f, 0.f, 0.f, 0.f};
    float m_i[2][4], l_i[2][4];
#pragma unroll
    for (int s = 0; s < 2; ++s)
#pragma unroll
        for (int r = 0; r < 4; ++r) { m_i[s][r] = NEG_BIG; l_i[s][r] = 0.f; }

    const float scale = 0.08838834764831845f;  // 1/sqrt(128)
    const int nsteps = q0 / 32 + 1;

    for (int jt = 0; jt < nsteps; ++jt) {
        const int j0 = jt * 32;
        const bool last = (jt == nsteps - 1);

        bf16x8 kf[2][4];
#pragma unroll
        for (int jc = 0; jc < 2; ++jc) {
            const bf16_t* kp = kbase + (size_t)(j0 + jc * 16 + col) * KV_DIM + quad * 8;
#pragma unroll
            for (int t = 0; t < 4; ++t) kf[jc][t] = *(const bf16x8*)(kp + t * 32);
        }
        bf16x8 vf[8];
#pragma unroll
        for (int dt = 0; dt < 8; ++dt)
            vf[dt] = *(const bf16x8*)(vtb + (size_t)(dt * 16 + col) * S_LEN +
                                      j0 + quad * 8);

#pragma unroll
        for (int s = 0; s < 2; ++s) {
            f32x4 sc[2];
            sc[0] = (f32x4){0.f, 0.f, 0.f, 0.f};
            sc[1] = (f32x4){0.f, 0.f, 0.f, 0.f};
#pragma unroll
            for (int jc = 0; jc < 2; ++jc)
#pragma unroll
                for (int t = 0; t < 4; ++t)
                    sc[jc] = mfma16x16x32(aQ[s][t], kf[jc][t], sc[jc]);

            const int qrow = q0 + s * 16 + quad * 4;
#pragma unroll
            for (int jc = 0; jc < 2; ++jc) {
                const int j = j0 + jc * 16 + col;
#pragma unroll
                for (int r = 0; r < 4; ++r) {
                    float v = sc[jc][r] * scale;
                    if (last) v = (j <= qrow + r) ? v : NEG_BIG;
                    sc[jc][r] = v;
                }
            }
            float alpha[4];
#pragma unroll
            for (int r = 0; r < 4; ++r) {
                float v = fmaxf(sc[0][r], sc[1][r]);
                v = fmaxf(v, __shfl_xor(v, 1, 16));
                v = fmaxf(v, __shfl_xor(v, 2, 16));
                v = fmaxf(v, __shfl_xor(v, 4, 16));
                v = fmaxf(v, __shfl_xor(v, 8, 16));
                const float mn = fmaxf(m_i[s][r], v);
                alpha[r] = __expf(m_i[s][r] - mn);
                m_i[s][r] = mn;
            }
#pragma unroll
            for (int r = 0; r < 4; ++r) {
                const float p0 = __expf(sc[0][r] - m_i[s][r]);
                const float p1 = __expf(sc[1][r] - m_i[s][r]);
                sc[0][r] = p0; sc[1][r] = p1;
                float v = p0 + p1;
                v += __shfl_xor(v, 1, 16);
                v += __shfl_xor(v, 2, 16);
                v += __shfl_xor(v, 4, 16);
                v += __shfl_xor(v, 8, 16);
                l_i[s][r] = l_i[s][r] * alpha[r] + v;
            }
#pragma unroll
            for (int dt = 0; dt < 8; ++dt)
#pragma unroll
                for (int r = 0; r < 4; ++r) Oacc[s][dt][r] *= alpha[r];
#pragma unroll
            for (int jc = 0; jc < 2; ++jc)
#pragma unroll
                for (int r = 0; r < 4; ++r)
                    Pb[wave][s][quad * 4 + r][jc * 16 + col] = (bf16_t)sc[jc][r];
        }
        asm volatile("s_waitcnt lgkmcnt(0)" ::: "memory");  // same-wave P visib.
#pragma unroll
        for (int s = 0; s < 2; ++s) {
            const bf16x8 aP = *(const bf16x8*)(&Pb[wave][s][col][quad * 8]);
#pragma unroll
            for (int dt = 0; dt < 8; ++dt)
                Oacc[s][dt] = mfma16x16x32(aP, vf[dt], Oacc[s][dt]);
        }
    }

#pragma unroll
    for (int s = 0; s < 2; ++s)
#pragma unroll
        for (int r = 0; r < 4; ++r) {
            const float inv = 1.0f / l_i[s][r];
            const size_t rowoff =
                (size_t)(b * S_LEN + q0 + s * 16 + quad * 4 + r) * H_DIM +
                h * HEAD_DIM;
#pragma unroll
            for (int dt = 0; dt < 8; ++dt)
                Q[rowoff + dt * 16 + col] = (bf16_t)(Oacc[s][dt][r] * inv);
        }
}

extern "C" void kernel_launch(void* const* d_in, const int* in_sizes, int n_in,
                              void* d_out, int out_size, void* d_ws, size_t ws_size,
                              hipStream_t stream) {
    const float* X    = (const float*)d_in[0];
    const float* cosb = (const float*)d_in[1];
    const float* sinb = (const float*)d_in[2];
    const float* Wq   = (const float*)d_in[3];
    const float* Wk   = (const float*)d_in[4];
    const float* Wv   = (const float*)d_in[5];
    const float* Wo   = (const float*)d_in[6];
    float* out = (float*)d_out;

    // ws (bf16): Xb 16MB | Wqb 8 | Wkb 2 | Wvb 2 | Wob 8 | Q 16 | K 4 | V^T 4
    char* ws = (char*)d_ws;
    bf16_t* Xb   = (bf16_t*)(ws);
    bf16_t* Wqb  = (bf16_t*)(ws + (16u << 20));
    bf16_t* Wkb  = (bf16_t*)(ws + (24u << 20));
    bf16_t* Wvb  = (bf16_t*)(ws + (26u << 20));
    bf16_t* Wob  = (bf16_t*)(ws + (28u << 20));
    bf16_t* qbuf = (bf16_t*)(ws + (36u << 20));
    bf16_t* kbuf = (bf16_t*)(ws + (52u << 20));
    bf16_t* vtbuf= (bf16_t*)(ws + (56u << 20));

    dim3 blk(256, 1, 1);
    const int nX = NTOK * H_DIM, nWq = H_DIM * H_DIM, nWk = KV_DIM * H_DIM;
    cvt_f32_bf16<<<dim3(nX / 2048, 1, 1), blk, 0, stream>>>(X, Xb, nX);
    cvt_f32_bf16<<<dim3(nWq / 2048, 1, 1), blk, 0, stream>>>(Wq, Wqb, nWq);
    cvt_f32_bf16<<<dim3(nWk / 2048, 1, 1), blk, 0, stream>>>(Wk, Wkb, nWk);
    cvt_f32_bf16<<<dim3(nWk / 2048, 1, 1), blk, 0, stream>>>(Wv, Wvb, nWk);
    cvt_f32_bf16<<<dim3(nWq / 2048, 1, 1), blk, 0, stream>>>(Wo, Wob, nWq);

    gemm_bt<bf16_t, false><<<dim3(H_DIM / 128, NTOK / 128), blk, 0, stream>>>(
        Xb, Wqb, qbuf, NTOK, H_DIM, H_DIM);
    gemm_bt<bf16_t, false><<<dim3(KV_DIM / 128, NTOK / 128), blk, 0, stream>>>(
        Xb, Wkb, kbuf, NTOK, KV_DIM, H_DIM);
    gemm_bt<bf16_t, true><<<dim3(KV_DIM / 128, NTOK / 128), blk, 0, stream>>>(
        Xb, Wvb, vtbuf, NTOK, KV_DIM, H_DIM);
    rope_inplace<<<dim3((NTOK * 20 * 64) / 256), blk, 0, stream>>>(qbuf, kbuf, cosb, sinb);
    attn_fwd<<<dim3(S_LEN / 32, KVHEADS, 2), blk, 0, stream>>>(qbuf, kbuf, vtbuf);
    gemm_bt<float, false><<<dim3(H_DIM / 128, NTOK / 128), blk, 0, stream>>>(
        qbuf, Wob, out, NTOK, H_DIM, H_DIM);

    (void)in_sizes; (void)n_in; (void)out_size; (void)ws_size;
}

// Round 4
// 570.917 us; speedup vs baseline: 1.3340x; 1.0749x over previous
//
#include <hip/hip_runtime.h>
#include <hip/hip_bf16.h>
#include <stdint.h>

#define S_LEN 2048
#define H_DIM 2048
#define NHEADS 16
#define KVHEADS 4
#define HEAD_DIM 128
#define KV_DIM 512       // KVHEADS * HEAD_DIM
#define NTOK 4096        // B * S

typedef __bf16 bf16_t;
typedef __bf16 bf16x8 __attribute__((ext_vector_type(8)));
typedef __bf16 bf16x4 __attribute__((ext_vector_type(4)));
typedef float f32x4 __attribute__((ext_vector_type(4)));

__device__ __forceinline__ f32x4 mfma16x16x32(bf16x8 a, bf16x8 b, f32x4 c) {
    return __builtin_amdgcn_mfma_f32_16x16x32_bf16(a, b, c, 0, 0, 0);
}

// async global->LDS, 16B per lane. LDS dest is wave-uniform base + lane*16.
__device__ __forceinline__ void gload_lds16(const bf16_t* g, bf16_t* l) {
    __builtin_amdgcn_global_load_lds(
        (__attribute__((address_space(1))) uint32_t*)(uintptr_t)g,
        (__attribute__((address_space(3))) uint32_t*)l, 16, 0, 0);
}

// fp32 -> bf16 bulk convert; n must be a multiple of 8.
__global__ __launch_bounds__(256) void cvt_f32_bf16(const float* __restrict__ src,
                                                    bf16_t* __restrict__ dst, int n) {
    const int i = (blockIdx.x * 256 + threadIdx.x) * 8;
    if (i >= n) return;
    const float4 a = *(const float4*)(src + i);
    const float4 b = *(const float4*)(src + i + 4);
    bf16x8 o;
    o[0] = (bf16_t)a.x; o[1] = (bf16_t)a.y; o[2] = (bf16_t)a.z; o[3] = (bf16_t)a.w;
    o[4] = (bf16_t)b.x; o[5] = (bf16_t)b.y; o[6] = (bf16_t)b.z; o[7] = (bf16_t)b.w;
    *(bf16x8*)(dst + i) = o;
}

// C[m][n] = sum_k A[m][k] * W[n][k]. m97 structure: 128x128 tile, BK=32,
// global_load_lds width-16 staging, ds_read_b128 fragments, 2x2 waves of
// 64x64. TRANS=true writes C transposed into V^T layout [b][kvh][d][s].
template <typename OutT, bool TRANS>
__global__ __launch_bounds__(256) void gemm_bt(const bf16_t* __restrict__ A,
                                               const bf16_t* __restrict__ W,
                                               OutT* __restrict__ C,
                                               int M, int N, int K) {
    __shared__ alignas(16) bf16_t As[128 * 32];
    __shared__ alignas(16) bf16_t Bs[128 * 32];
    const int tid  = threadIdx.x;
    const int wave = tid >> 6;
    const int lane = tid & 63;
    const int col  = lane & 15;
    const int quad = lane >> 4;
    const int m0 = blockIdx.y * 128;
    const int n0 = blockIdx.x * 128;
    const int wm = (wave >> 1) * 64;
    const int wn = (wave & 1) * 64;

    const int r0 = tid >> 2;
    const int kk = (tid & 3) * 8;
    const bf16_t* a0 = A + (size_t)(m0 + r0) * K + kk;
    const bf16_t* a1 = a0 + (size_t)64 * K;
    const bf16_t* b0 = W + (size_t)(n0 + r0) * K + kk;
    const bf16_t* b1 = b0 + (size_t)64 * K;
    bf16_t* lA0 = As + tid * 8;
    bf16_t* lA1 = As + 2048 + tid * 8;
    bf16_t* lB0 = Bs + tid * 8;
    bf16_t* lB1 = Bs + 2048 + tid * 8;

    f32x4 acc[4][4];
#pragma unroll
    for (int mi = 0; mi < 4; ++mi)
#pragma unroll
        for (int ni = 0; ni < 4; ++ni)
            acc[mi][ni] = (f32x4){0.f, 0.f, 0.f, 0.f};

    for (int k0 = 0; k0 < K; k0 += 32) {
        __syncthreads();
        gload_lds16(a0 + k0, lA0);
        gload_lds16(a1 + k0, lA1);
        gload_lds16(b0 + k0, lB0);
        gload_lds16(b1 + k0, lB1);
        __syncthreads();
        bf16x8 av[4], bv[4];
#pragma unroll
        for (int i = 0; i < 4; ++i) {
            av[i] = *(const bf16x8*)(As + (wm + i * 16 + col) * 32 + quad * 8);
            bv[i] = *(const bf16x8*)(Bs + (wn + i * 16 + col) * 32 + quad * 8);
        }
#pragma unroll
        for (int mi = 0; mi < 4; ++mi)
#pragma unroll
            for (int ni = 0; ni < 4; ++ni)
                acc[mi][ni] = mfma16x16x32(av[mi], bv[ni], acc[mi][ni]);
    }

    if constexpr (!TRANS) {
#pragma unroll
        for (int mi = 0; mi < 4; ++mi)
#pragma unroll
            for (int ni = 0; ni < 4; ++ni)
#pragma unroll
                for (int r = 0; r < 4; ++r)
                    C[(size_t)(m0 + wm + mi * 16 + quad * 4 + r) * N +
                      n0 + wn + ni * 16 + col] = (OutT)acc[mi][ni][r];
    } else {
#pragma unroll
        for (int mi = 0; mi < 4; ++mi) {
            const int m = m0 + wm + mi * 16 + quad * 4;
#pragma unroll
            for (int ni = 0; ni < 4; ++ni) {
                const int n = n0 + wn + ni * 16 + col;
                const size_t off =
                    ((size_t)(m >> 11) * KV_DIM + n) * S_LEN + (m & (S_LEN - 1));
                bf16x4 o;
#pragma unroll
                for (int r = 0; r < 4; ++r) o[r] = (bf16_t)acc[mi][ni][r];
                *(bf16x4*)((bf16_t*)C + off) = o;
            }
        }
    }
}

// In-place RoPE on Q [NTOK][2048] (16 heads) and K [NTOK][512] (4 heads).
__global__ __launch_bounds__(256) void rope_inplace(bf16_t* __restrict__ Qb,
                                                    bf16_t* __restrict__ Kb,
                                                    const float* __restrict__ cosb,
                                                    const float* __restrict__ sinb) {
    const int idx  = blockIdx.x * 256 + threadIdx.x;
    const int d    = idx & 63;
    const int rem  = idx >> 6;
    const int head = rem % 20;
    const int row  = rem / 20;
    if (row >= NTOK) return;
    const int s = row & (S_LEN - 1);
    const float c0 = cosb[s * HEAD_DIM + d];
    const float s0 = sinb[s * HEAD_DIM + d];
    const float c1 = cosb[s * HEAD_DIM + 64 + d];
    const float s1 = sinb[s * HEAD_DIM + 64 + d];
    bf16_t* base = (head < NHEADS)
        ? Qb + (size_t)row * H_DIM + head * HEAD_DIM
        : Kb + (size_t)row * KV_DIM + (head - NHEADS) * HEAD_DIM;
    const float lo = (float)base[d];
    const float hi = (float)base[d + 64];
    base[d]      = (bf16_t)(lo * c0 - hi * s0);
    base[d + 64] = (bf16_t)(hi * c1 + lo * s1);
}

#define NEG_BIG (-1e30f)

// Flash attention, causal, transposed-score formulation (S^T = K.Q^T so the
// softmax reduction over kv is in-lane + 2 butterfly shuffles). Block =
// (pair p, kvh, b); 4 waves = 4 GQA heads; each wave handles the 16-row
// q-tiles {p, 127-p} sequentially -> every block runs exactly 65 kv-steps
// (perfect static balance). K/V fragments double-buffered in registers.
// Output written in place into Q (each (tile,head) region owned by 1 wave).
__global__ __launch_bounds__(256, 2) void attn_fwd(bf16_t* __restrict__ Q,
                                                   const bf16_t* __restrict__ Kb,
                                                   const bf16_t* __restrict__ Vt) {
    const int p   = blockIdx.x;        // 0..63
    const int kvh = blockIdx.y;
    const int b   = blockIdx.z;
    const int wave = threadIdx.x >> 6;
    const int lane = threadIdx.x & 63;
    const int col  = lane & 15;
    const int quad = lane >> 4;
    const int h = kvh * 4 + wave;

    __shared__ alignas(16) bf16_t Pt[4][16][40];   // [wave][q][j] pad->2-way

    const bf16_t* kbase = Kb + (size_t)(b * S_LEN) * KV_DIM + kvh * HEAD_DIM;
    const bf16_t* vtb   = Vt + (size_t)(b * KVHEADS + kvh) * HEAD_DIM * S_LEN;
    const float scale = 0.08838834764831845f;  // 1/sqrt(128)

    int q0, nsteps;
    bf16x8 qf[4];
    f32x4 Oacc[8];
    float m_i, l_i;
    bf16x8 kfA[2][4], vfA[8], kfB[2][4], vfB[8];

    auto load_kv = [&](int j0, bf16x8 (&kf)[2][4], bf16x8 (&vf)[8]) {
        const int jj0 = j0 > (S_LEN - 32) ? (S_LEN - 32) : j0;  // prefetch clamp
#pragma unroll
        for (int jc = 0; jc < 2; ++jc) {
            const bf16_t* kp = kbase + (size_t)(jj0 + jc * 16 + col) * KV_DIM + quad * 8;
#pragma unroll
            for (int t = 0; t < 4; ++t) kf[jc][t] = *(const bf16x8*)(kp + t * 32);
        }
#pragma unroll
        for (int dt = 0; dt < 8; ++dt)
            vf[dt] = *(const bf16x8*)(vtb + (size_t)(dt * 16 + col) * S_LEN +
                                      jj0 + quad * 8);
    };

    // one 32-wide kv step; prefetches the next K/V tile into (kfn, vfn)
    auto step = [&](int jt, bf16x8 (&kf)[2][4], bf16x8 (&vf)[8],
                    bf16x8 (&kfn)[2][4], bf16x8 (&vfn)[8]) {
        const int j0 = jt * 32;
        const bool last = (jt == nsteps - 1);
        f32x4 sc[2];
        sc[0] = (f32x4){0.f, 0.f, 0.f, 0.f};
        sc[1] = (f32x4){0.f, 0.f, 0.f, 0.f};
#pragma unroll
        for (int jc = 0; jc < 2; ++jc)
#pragma unroll
            for (int t = 0; t < 4; ++t)
                sc[jc] = mfma16x16x32(kf[jc][t], qf[t], sc[jc]);   // S^T tile

        const int q = q0 + col;
#pragma unroll
        for (int jc = 0; jc < 2; ++jc)
#pragma unroll
            for (int r = 0; r < 4; ++r) {
                float v = sc[jc][r] * scale;
                if (last) {
                    const int j = j0 + jc * 16 + quad * 4 + r;
                    v = (j <= q) ? v : NEG_BIG;
                }
                sc[jc][r] = v;
            }
        // column (q) max: 8 in-lane + butterfly across quads
        float mx = fmaxf(fmaxf(fmaxf(sc[0][0], sc[0][1]), fmaxf(sc[0][2], sc[0][3])),
                         fmaxf(fmaxf(sc[1][0], sc[1][1]), fmaxf(sc[1][2], sc[1][3])));
        mx = fmaxf(mx, __shfl_xor(mx, 16));
        mx = fmaxf(mx, __shfl_xor(mx, 32));
        const float mn = fmaxf(m_i, mx);
        const float alpha = __expf(m_i - mn);
        m_i = mn;
        float s00 = __expf(sc[0][0] - mn), s01 = __expf(sc[0][1] - mn);
        float s02 = __expf(sc[0][2] - mn), s03 = __expf(sc[0][3] - mn);
        float s10 = __expf(sc[1][0] - mn), s11 = __expf(sc[1][1] - mn);
        float s12 = __expf(sc[1][2] - mn), s13 = __expf(sc[1][3] - mn);
        float sum = ((s00 + s01) + (s02 + s03)) + ((s10 + s11) + (s12 + s13));
        sum += __shfl_xor(sum, 16);
        sum += __shfl_xor(sum, 32);
        l_i = l_i * alpha + sum;
        // write P^T: lane holds P[q=col][j= jc*16+quad*4 + 0..3] -> one b64/jc
        {
            bf16x4 w0; w0[0] = (bf16_t)s00; w0[1] = (bf16_t)s01;
            w0[2] = (bf16_t)s02; w0[3] = (bf16_t)s03;
            *(bf16x4*)(&Pt[wave][col][quad * 4]) = w0;
            bf16x4 w1; w1[0] = (bf16_t)s10; w1[1] = (bf16_t)s11;
            w1[2] = (bf16_t)s12; w1[3] = (bf16_t)s13;
            *(bf16x4*)(&Pt[wave][col][16 + quad * 4]) = w1;
        }
        // broadcast alpha (per q=col) to O rows (q=quad*4+r), rescale O
        float ar[4];
#pragma unroll
        for (int r = 0; r < 4; ++r) ar[r] = __shfl(alpha, quad * 4 + r, 16);
#pragma unroll
        for (int dt = 0; dt < 8; ++dt)
#pragma unroll
            for (int r = 0; r < 4; ++r) Oacc[dt][r] *= ar[r];
        // prefetch next K/V tile before draining the LDS queue
        load_kv(j0 + 32, kfn, vfn);
        asm volatile("s_waitcnt lgkmcnt(0)" ::: "memory");
        const bf16x8 aP = *(const bf16x8*)(&Pt[wave][col][quad * 8]);
#pragma unroll
        for (int dt = 0; dt < 8; ++dt)
            Oacc[dt] = mfma16x16x32(aP, vf[dt], Oacc[dt]);
    };

#pragma unroll 1
    for (int half = 0; half < 2; ++half) {
        const int qt = half ? (127 - p) : p;
        q0 = qt * 16;
        nsteps = (qt >> 1) + 1;
        {
            const bf16_t* qp = Q + (size_t)(b * S_LEN + q0 + col) * H_DIM +
                               h * HEAD_DIM + quad * 8;
#pragma unroll
            for (int t = 0; t < 4; ++t) qf[t] = *(const bf16x8*)(qp + t * 32);
        }
#pragma unroll
        for (int dt = 0; dt < 8; ++dt) Oacc[dt] = (f32x4){0.f, 0.f, 0.f, 0.f};
        m_i = NEG_BIG; l_i = 0.f;

        load_kv(0, kfA, vfA);
        for (int jt = 0; jt < nsteps; jt += 2) {
            step(jt, kfA, vfA, kfB, vfB);
            if (jt + 1 < nsteps) step(jt + 1, kfB, vfB, kfA, vfA);
        }
        // normalize (broadcast l to O rows) and store in place
        float lr[4];
#pragma unroll
        for (int r = 0; r < 4; ++r) lr[r] = __shfl(l_i, quad * 4 + r, 16);
#pragma unroll
        for (int r = 0; r < 4; ++r) {
            const float inv = 1.0f / lr[r];
            const size_t rowoff =
                (size_t)(b * S_LEN + q0 + quad * 4 + r) * H_DIM + h * HEAD_DIM;
#pragma unroll
            for (int dt = 0; dt < 8; ++dt)
                Q[rowoff + dt * 16 + col] = (bf16_t)(Oacc[dt][r] * inv);
        }
    }
}

extern "C" void kernel_launch(void* const* d_in, const int* in_sizes, int n_in,
                              void* d_out, int out_size, void* d_ws, size_t ws_size,
                              hipStream_t stream) {
    const float* X    = (const float*)d_in[0];
    const float* cosb = (const float*)d_in[1];
    const float* sinb = (const float*)d_in[2];
    const float* Wq   = (const float*)d_in[3];
    const float* Wk   = (const float*)d_in[4];
    const float* Wv   = (const float*)d_in[5];
    const float* Wo   = (const float*)d_in[6];
    float* out = (float*)d_out;

    // ws (bf16): Xb 16MB | Wqb 8 | Wkb 2 | Wvb 2 | Wob 8 | Q 16 | K 4 | V^T 4
    char* ws = (char*)d_ws;
    bf16_t* Xb   = (bf16_t*)(ws);
    bf16_t* Wqb  = (bf16_t*)(ws + (16u << 20));
    bf16_t* Wkb  = (bf16_t*)(ws + (24u << 20));
    bf16_t* Wvb  = (bf16_t*)(ws + (26u << 20));
    bf16_t* Wob  = (bf16_t*)(ws + (28u << 20));
    bf16_t* qbuf = (bf16_t*)(ws + (36u << 20));
    bf16_t* kbuf = (bf16_t*)(ws + (52u << 20));
    bf16_t* vtbuf= (bf16_t*)(ws + (56u << 20));

    dim3 blk(256, 1, 1);
    const int nX = NTOK * H_DIM, nWq = H_DIM * H_DIM, nWk = KV_DIM * H_DIM;
    cvt_f32_bf16<<<dim3(nX / 2048, 1, 1), blk, 0, stream>>>(X, Xb, nX);
    cvt_f32_bf16<<<dim3(nWq / 2048, 1, 1), blk, 0, stream>>>(Wq, Wqb, nWq);
    cvt_f32_bf16<<<dim3(nWk / 2048, 1, 1), blk, 0, stream>>>(Wk, Wkb, nWk);
    cvt_f32_bf16<<<dim3(nWk / 2048, 1, 1), blk, 0, stream>>>(Wv, Wvb, nWk);
    cvt_f32_bf16<<<dim3(nWq / 2048, 1, 1), blk, 0, stream>>>(Wo, Wob, nWq);

    gemm_bt<bf16_t, false><<<dim3(H_DIM / 128, NTOK / 128), blk, 0, stream>>>(
        Xb, Wqb, qbuf, NTOK, H_DIM, H_DIM);
    gemm_bt<bf16_t, false><<<dim3(KV_DIM / 128, NTOK / 128), blk, 0, stream>>>(
        Xb, Wkb, kbuf, NTOK, KV_DIM, H_DIM);
    gemm_bt<bf16_t, true><<<dim3(KV_DIM / 128, NTOK / 128), blk, 0, stream>>>(
        Xb, Wvb, vtbuf, NTOK, KV_DIM, H_DIM);
    rope_inplace<<<dim3((NTOK * 20 * 64) / 256), blk, 0, stream>>>(qbuf, kbuf, cosb, sinb);
    attn_fwd<<<dim3(64, KVHEADS, 2), blk, 0, stream>>>(qbuf, kbuf, vtbuf);
    gemm_bt<float, false><<<dim3(H_DIM / 128, NTOK / 128), blk, 0, stream>>>(
        qbuf, Wob, out, NTOK, H_DIM, H_DIM);

    (void)in_sizes; (void)n_in; (void)out_size; (void)ws_size;
}

// Round 5
// 411.659 us; speedup vs baseline: 1.8500x; 1.3869x over previous
//
#include <hip/hip_runtime.h>
#include <hip/hip_bf16.h>
#include <stdint.h>

#define S_LEN 2048
#define H_DIM 2048
#define NHEADS 16
#define KVHEADS 4
#define HEAD_DIM 128
#define KV_DIM 512       // KVHEADS * HEAD_DIM
#define NTOK 4096        // B * S

typedef __bf16 bf16_t;
typedef __bf16 bf16x8 __attribute__((ext_vector_type(8)));
typedef __bf16 bf16x4 __attribute__((ext_vector_type(4)));
typedef float f32x4 __attribute__((ext_vector_type(4)));

__device__ __forceinline__ f32x4 mfma16x16x32(bf16x8 a, bf16x8 b, f32x4 c) {
    return __builtin_amdgcn_mfma_f32_16x16x32_bf16(a, b, c, 0, 0, 0);
}

// async global->LDS, 16B per lane. LDS dest is wave-uniform base + lane*16.
__device__ __forceinline__ void gload_lds16(const bf16_t* g, bf16_t* l) {
    __builtin_amdgcn_global_load_lds(
        (__attribute__((address_space(1))) uint32_t*)(uintptr_t)g,
        (__attribute__((address_space(3))) uint32_t*)l, 16, 0, 0);
}

// Fused fp32->bf16 convert of all 5 tensors in one launch (8 elems/thread).
#define N_X  (NTOK * H_DIM)     // 8388608
#define N_WQ (H_DIM * H_DIM)    // 4194304
#define N_WK (KV_DIM * H_DIM)   // 1048576
__global__ __launch_bounds__(256) void cvt_all(const float* __restrict__ X,
                                               const float* __restrict__ Wq,
                                               const float* __restrict__ Wk,
                                               const float* __restrict__ Wv,
                                               const float* __restrict__ Wo,
                                               bf16_t* __restrict__ Xb,
                                               bf16_t* __restrict__ Wqb,
                                               bf16_t* __restrict__ Wkb,
                                               bf16_t* __restrict__ Wvb,
                                               bf16_t* __restrict__ Wob) {
    long i = (long)(blockIdx.x * 256 + threadIdx.x) * 8;
    const float* src;
    bf16_t* dst;
    if (i < N_X)                       { src = X;  dst = Xb; }
    else if ((i -= N_X) < N_WQ)        { src = Wq; dst = Wqb; }
    else if ((i -= N_WQ) < N_WK)       { src = Wk; dst = Wkb; }
    else if ((i -= N_WK) < N_WK)       { src = Wv; dst = Wvb; }
    else      { i -= N_WK;               src = Wo; dst = Wob; }
    const float4 a = *(const float4*)(src + i);
    const float4 b = *(const float4*)(src + i + 4);
    bf16x8 o;
    o[0] = (bf16_t)a.x; o[1] = (bf16_t)a.y; o[2] = (bf16_t)a.z; o[3] = (bf16_t)a.w;
    o[4] = (bf16_t)b.x; o[5] = (bf16_t)b.y; o[6] = (bf16_t)b.z; o[7] = (bf16_t)b.w;
    *(bf16x8*)(dst + i) = o;
}

// C[m][n] = sum_k A[m][k] * W[n][k]. m97 structure: 128x128 tile, BK=32,
// global_load_lds width-16 staging, ds_read_b128 fragments, 2x2 waves of
// 64x64. TRANS=true writes C transposed into V^T layout [b][kvh][d][s].
template <typename OutT, bool TRANS>
__global__ __launch_bounds__(256) void gemm_bt(const bf16_t* __restrict__ A,
                                               const bf16_t* __restrict__ W,
                                               OutT* __restrict__ C,
                                               int M, int N, int K) {
    __shared__ alignas(16) bf16_t As[128 * 32];
    __shared__ alignas(16) bf16_t Bs[128 * 32];
    const int tid  = threadIdx.x;
    const int wave = tid >> 6;
    const int lane = tid & 63;
    const int col  = lane & 15;
    const int quad = lane >> 4;
    const int m0 = blockIdx.y * 128;
    const int n0 = blockIdx.x * 128;
    const int wm = (wave >> 1) * 64;
    const int wn = (wave & 1) * 64;

    const int r0 = tid >> 2;
    const int kk = (tid & 3) * 8;
    const bf16_t* a0 = A + (size_t)(m0 + r0) * K + kk;
    const bf16_t* a1 = a0 + (size_t)64 * K;
    const bf16_t* b0 = W + (size_t)(n0 + r0) * K + kk;
    const bf16_t* b1 = b0 + (size_t)64 * K;
    bf16_t* lA0 = As + tid * 8;
    bf16_t* lA1 = As + 2048 + tid * 8;
    bf16_t* lB0 = Bs + tid * 8;
    bf16_t* lB1 = Bs + 2048 + tid * 8;

    f32x4 acc[4][4];
#pragma unroll
    for (int mi = 0; mi < 4; ++mi)
#pragma unroll
        for (int ni = 0; ni < 4; ++ni)
            acc[mi][ni] = (f32x4){0.f, 0.f, 0.f, 0.f};

    for (int k0 = 0; k0 < K; k0 += 32) {
        __syncthreads();
        gload_lds16(a0 + k0, lA0);
        gload_lds16(a1 + k0, lA1);
        gload_lds16(b0 + k0, lB0);
        gload_lds16(b1 + k0, lB1);
        __syncthreads();
        bf16x8 av[4], bv[4];
#pragma unroll
        for (int i = 0; i < 4; ++i) {
            av[i] = *(const bf16x8*)(As + (wm + i * 16 + col) * 32 + quad * 8);
            bv[i] = *(const bf16x8*)(Bs + (wn + i * 16 + col) * 32 + quad * 8);
        }
#pragma unroll
        for (int mi = 0; mi < 4; ++mi)
#pragma unroll
            for (int ni = 0; ni < 4; ++ni)
                acc[mi][ni] = mfma16x16x32(av[mi], bv[ni], acc[mi][ni]);
    }

    if constexpr (!TRANS) {
#pragma unroll
        for (int mi = 0; mi < 4; ++mi)
#pragma unroll
            for (int ni = 0; ni < 4; ++ni)
#pragma unroll
                for (int r = 0; r < 4; ++r)
                    C[(size_t)(m0 + wm + mi * 16 + quad * 4 + r) * N +
                      n0 + wn + ni * 16 + col] = (OutT)acc[mi][ni][r];
    } else {
#pragma unroll
        for (int mi = 0; mi < 4; ++mi) {
            const int m = m0 + wm + mi * 16 + quad * 4;
#pragma unroll
            for (int ni = 0; ni < 4; ++ni) {
                const int n = n0 + wn + ni * 16 + col;
                const size_t off =
                    ((size_t)(m >> 11) * KV_DIM + n) * S_LEN + (m & (S_LEN - 1));
                bf16x4 o;
#pragma unroll
                for (int r = 0; r < 4; ++r) o[r] = (bf16_t)acc[mi][ni][r];
                *(bf16x4*)((bf16_t*)C + off) = o;
            }
        }
    }
}

// In-place RoPE on Q [NTOK][2048] (16 heads) and K [NTOK][512] (4 heads).
__global__ __launch_bounds__(256) void rope_inplace(bf16_t* __restrict__ Qb,
                                                    bf16_t* __restrict__ Kb,
                                                    const float* __restrict__ cosb,
                                                    const float* __restrict__ sinb) {
    const int idx  = blockIdx.x * 256 + threadIdx.x;
    const int d    = idx & 63;
    const int rem  = idx >> 6;
    const int head = rem % 20;
    const int row  = rem / 20;
    if (row >= NTOK) return;
    const int s = row & (S_LEN - 1);
    const float c0 = cosb[s * HEAD_DIM + d];
    const float s0 = sinb[s * HEAD_DIM + d];
    const float c1 = cosb[s * HEAD_DIM + 64 + d];
    const float s1 = sinb[s * HEAD_DIM + 64 + d];
    bf16_t* base = (head < NHEADS)
        ? Qb + (size_t)row * H_DIM + head * HEAD_DIM
        : Kb + (size_t)row * KV_DIM + (head - NHEADS) * HEAD_DIM;
    const float lo = (float)base[d];
    const float hi = (float)base[d + 64];
    base[d]      = (bf16_t)(lo * c0 - hi * s0);
    base[d + 64] = (bf16_t)(hi * c1 + lo * s1);
}

#define NEG_BIG (-1e30f)

// Flash attention, causal, transposed-score formulation. Block = (pair p,
// kvh, b); 4 waves = 4 GQA heads sharing this kv head; q-tiles {p, 127-p}
// done sequentially -> every block runs exactly 65 kv-steps. K/V tiles are
// staged ONCE per block into double-buffered LDS (shared by all 4 waves;
// kills the round-4 register-spill L2 storm and cuts L2 reads 4x). Global
// prefetch for tile j+1 is issued at step top and ds_written at step
// bottom -> loads in flight across the whole step. One barrier per step.
// Output written in place into Q (each (tile,head) region owned by 1 wave).
__global__ __launch_bounds__(256, 2) void attn_fwd(bf16_t* __restrict__ Q,
                                                   const bf16_t* __restrict__ Kb,
                                                   const bf16_t* __restrict__ Vt) {
    const int p   = blockIdx.x;        // 0..63
    const int kvh = blockIdx.y;
    const int b   = blockIdx.z;
    const int tid  = threadIdx.x;
    const int wave = tid >> 6;
    const int lane = tid & 63;
    const int col  = lane & 15;
    const int quad = lane >> 4;
    const int h = kvh * 4 + wave;

    // K tile [j=32][d=128] pad->136 (b128 spans tile all 32 banks);
    // V^T tile [d=128][j=32] pad->40; P^T roundtrip per-wave.
    __shared__ alignas(16) bf16_t Ks[2][32][136];
    __shared__ alignas(16) bf16_t Vs[2][128][40];
    __shared__ alignas(16) bf16_t Pt[4][16][40];

    const bf16_t* kbase = Kb + (size_t)(b * S_LEN) * KV_DIM + kvh * HEAD_DIM;
    const bf16_t* vtb   = Vt + (size_t)(b * KVHEADS + kvh) * HEAD_DIM * S_LEN;
    const float scale = 0.08838834764831845f;  // 1/sqrt(128)

    // per-thread staging map (64B/thread/tile)
    const int kr = tid >> 3, ko = (tid & 7) * 16;   // K: row 0..31, elem off
    const int vr = tid >> 1, vo = (tid & 1) * 16;   // V^T: row 0..127, elem off
    const bf16_t* kgp = kbase + (size_t)kr * KV_DIM + ko;
    const bf16_t* vgp = vtb + (size_t)vr * S_LEN + vo;

#pragma unroll 1
    for (int half = 0; half < 2; ++half) {
        const int qt = half ? (127 - p) : p;
        const int q0 = qt * 16;
        const int nsteps = (qt >> 1) + 1;

        bf16x8 qf[4];
        {
            const bf16_t* qp = Q + (size_t)(b * S_LEN + q0 + col) * H_DIM +
                               h * HEAD_DIM + quad * 8;
#pragma unroll
            for (int t = 0; t < 4; ++t) qf[t] = *(const bf16x8*)(qp + t * 32);
        }
        f32x4 Oacc[8];
#pragma unroll
        for (int dt = 0; dt < 8; ++dt) Oacc[dt] = (f32x4){0.f, 0.f, 0.f, 0.f};
        float m_i = NEG_BIG, l_i = 0.f;

        // stage tile 0 into buf 0
        {
            bf16x8 gk0 = *(const bf16x8*)kgp;
            bf16x8 gk1 = *(const bf16x8*)(kgp + 8);
            bf16x8 gv0 = *(const bf16x8*)vgp;
            bf16x8 gv1 = *(const bf16x8*)(vgp + 8);
            __syncthreads();   // protect buf0 from previous half's readers
            *(bf16x8*)(&Ks[0][kr][ko])     = gk0;
            *(bf16x8*)(&Ks[0][kr][ko + 8]) = gk1;
            *(bf16x8*)(&Vs[0][vr][vo])     = gv0;
            *(bf16x8*)(&Vs[0][vr][vo + 8]) = gv1;
        }

        for (int jt = 0; jt < nsteps; ++jt) {
            const int cur = jt & 1;
            const bool last = (jt == nsteps - 1);
            __syncthreads();   // staged writes for buf cur visible

            // prefetch next tile into registers (in flight across this step)
            bf16x8 gk0, gk1, gv0, gv1;
            if (!last) {
                const size_t joff = (size_t)(jt + 1) * 32;
                gk0 = *(const bf16x8*)(kgp + joff * KV_DIM);
                gk1 = *(const bf16x8*)(kgp + joff * KV_DIM + 8);
                gv0 = *(const bf16x8*)(vgp + joff);
                gv1 = *(const bf16x8*)(vgp + joff + 8);
            }

            // S^T(32x16) = K . Q^T
            f32x4 sc[2];
            sc[0] = (f32x4){0.f, 0.f, 0.f, 0.f};
            sc[1] = (f32x4){0.f, 0.f, 0.f, 0.f};
#pragma unroll
            for (int jc = 0; jc < 2; ++jc)
#pragma unroll
                for (int t = 0; t < 4; ++t) {
                    const bf16x8 kf =
                        *(const bf16x8*)(&Ks[cur][jc * 16 + col][t * 32 + quad * 8]);
                    sc[jc] = mfma16x16x32(kf, qf[t], sc[jc]);
                }

            const int j0 = jt * 32;
            const int q = q0 + col;
#pragma unroll
            for (int jc = 0; jc < 2; ++jc)
#pragma unroll
                for (int r = 0; r < 4; ++r) {
                    float v = sc[jc][r] * scale;
                    if (last) {
                        const int j = j0 + jc * 16 + quad * 4 + r;
                        v = (j <= q) ? v : NEG_BIG;
                    }
                    sc[jc][r] = v;
                }
            // column (q) max: in-lane tree + 2 butterfly shuffles
            float mx = fmaxf(fmaxf(fmaxf(sc[0][0], sc[0][1]), fmaxf(sc[0][2], sc[0][3])),
                             fmaxf(fmaxf(sc[1][0], sc[1][1]), fmaxf(sc[1][2], sc[1][3])));
            mx = fmaxf(mx, __shfl_xor(mx, 16));
            mx = fmaxf(mx, __shfl_xor(mx, 32));
            const float mn = fmaxf(m_i, mx);
            const float alpha = __expf(m_i - mn);
            m_i = mn;
            float s00 = __expf(sc[0][0] - mn), s01 = __expf(sc[0][1] - mn);
            float s02 = __expf(sc[0][2] - mn), s03 = __expf(sc[0][3] - mn);
            float s10 = __expf(sc[1][0] - mn), s11 = __expf(sc[1][1] - mn);
            float s12 = __expf(sc[1][2] - mn), s13 = __expf(sc[1][3] - mn);
            float sum = ((s00 + s01) + (s02 + s03)) + ((s10 + s11) + (s12 + s13));
            sum += __shfl_xor(sum, 16);
            sum += __shfl_xor(sum, 32);
            l_i = l_i * alpha + sum;
            // write P^T back as [q][j]
            {
                bf16x4 w0; w0[0] = (bf16_t)s00; w0[1] = (bf16_t)s01;
                w0[2] = (bf16_t)s02; w0[3] = (bf16_t)s03;
                *(bf16x4*)(&Pt[wave][col][quad * 4]) = w0;
                bf16x4 w1; w1[0] = (bf16_t)s10; w1[1] = (bf16_t)s11;
                w1[2] = (bf16_t)s12; w1[3] = (bf16_t)s13;
                *(bf16x4*)(&Pt[wave][col][16 + quad * 4]) = w1;
            }
            // broadcast alpha (per q=col) to O rows (q=quad*4+r), rescale O
            float ar[4];
#pragma unroll
            for (int r = 0; r < 4; ++r) ar[r] = __shfl(alpha, quad * 4 + r, 16);
#pragma unroll
            for (int dt = 0; dt < 8; ++dt)
#pragma unroll
                for (int r = 0; r < 4; ++r) Oacc[dt][r] *= ar[r];

            asm volatile("s_waitcnt lgkmcnt(0)" ::: "memory");  // P visible
            const bf16x8 aP = *(const bf16x8*)(&Pt[wave][col][quad * 8]);
#pragma unroll
            for (int dt = 0; dt < 8; ++dt) {
                const bf16x8 vf =
                    *(const bf16x8*)(&Vs[cur][dt * 16 + col][quad * 8]);
                Oacc[dt] = mfma16x16x32(aP, vf, Oacc[dt]);
            }

            // commit prefetched tile into the other buffer
            if (!last) {
                const int nxt = cur ^ 1;
                *(bf16x8*)(&Ks[nxt][kr][ko])     = gk0;
                *(bf16x8*)(&Ks[nxt][kr][ko + 8]) = gk1;
                *(bf16x8*)(&Vs[nxt][vr][vo])     = gv0;
                *(bf16x8*)(&Vs[nxt][vr][vo + 8]) = gv1;
            }
        }

        // normalize (broadcast l to O rows) and store in place
        float lr[4];
#pragma unroll
        for (int r = 0; r < 4; ++r) lr[r] = __shfl(l_i, quad * 4 + r, 16);
#pragma unroll
        for (int r = 0; r < 4; ++r) {
            const float inv = 1.0f / lr[r];
            const size_t rowoff =
                (size_t)(b * S_LEN + q0 + quad * 4 + r) * H_DIM + h * HEAD_DIM;
#pragma unroll
            for (int dt = 0; dt < 8; ++dt)
                Q[rowoff + dt * 16 + col] = (bf16_t)(Oacc[dt][r] * inv);
        }
    }
}

extern "C" void kernel_launch(void* const* d_in, const int* in_sizes, int n_in,
                              void* d_out, int out_size, void* d_ws, size_t ws_size,
                              hipStream_t stream) {
    const float* X    = (const float*)d_in[0];
    const float* cosb = (const float*)d_in[1];
    const float* sinb = (const float*)d_in[2];
    const float* Wq   = (const float*)d_in[3];
    const float* Wk   = (const float*)d_in[4];
    const float* Wv   = (const float*)d_in[5];
    const float* Wo   = (const float*)d_in[6];
    float* out = (float*)d_out;

    // ws (bf16): Xb 16MB | Wqb 8 | Wkb 2 | Wvb 2 | Wob 8 | Q 16 | K 4 | V^T 4
    char* ws = (char*)d_ws;
    bf16_t* Xb   = (bf16_t*)(ws);
    bf16_t* Wqb  = (bf16_t*)(ws + (16u << 20));
    bf16_t* Wkb  = (bf16_t*)(ws + (24u << 20));
    bf16_t* Wvb  = (bf16_t*)(ws + (26u << 20));
    bf16_t* Wob  = (bf16_t*)(ws + (28u << 20));
    bf16_t* qbuf = (bf16_t*)(ws + (36u << 20));
    bf16_t* kbuf = (bf16_t*)(ws + (52u << 20));
    bf16_t* vtbuf= (bf16_t*)(ws + (56u << 20));

    dim3 blk(256, 1, 1);
    const int ncvt = N_X + 2 * N_WQ + 2 * N_WK;   // 18874368, /2048 = 9216
    cvt_all<<<dim3(ncvt / 2048, 1, 1), blk, 0, stream>>>(
        X, Wq, Wk, Wv, Wo, Xb, Wqb, Wkb, Wvb, Wob);

    gemm_bt<bf16_t, false><<<dim3(H_DIM / 128, NTOK / 128), blk, 0, stream>>>(
        Xb, Wqb, qbuf, NTOK, H_DIM, H_DIM);
    gemm_bt<bf16_t, false><<<dim3(KV_DIM / 128, NTOK / 128), blk, 0, stream>>>(
        Xb, Wkb, kbuf, NTOK, KV_DIM, H_DIM);
    gemm_bt<bf16_t, true><<<dim3(KV_DIM / 128, NTOK / 128), blk, 0, stream>>>(
        Xb, Wvb, vtbuf, NTOK, KV_DIM, H_DIM);
    rope_inplace<<<dim3((NTOK * 20 * 64) / 256), blk, 0, stream>>>(qbuf, kbuf, cosb, sinb);
    attn_fwd<<<dim3(64, KVHEADS, 2), blk, 0, stream>>>(qbuf, kbuf, vtbuf);
    gemm_bt<float, false><<<dim3(H_DIM / 128, NTOK / 128), blk, 0, stream>>>(
        qbuf, Wob, out, NTOK, H_DIM, H_DIM);

    (void)in_sizes; (void)n_in; (void)out_size; (void)ws_size;
}

// Round 6
// 312.014 us; speedup vs baseline: 2.4409x; 1.3194x over previous
//
#include <hip/hip_runtime.h>
#include <hip/hip_bf16.h>
#include <stdint.h>

#define S_LEN 2048
#define H_DIM 2048
#define NHEADS 16
#define KVHEADS 4
#define HEAD_DIM 128
#define KV_DIM 512       // KVHEADS * HEAD_DIM
#define NTOK 4096        // B * S
#define NQKV 3072        // H_DIM + 2*KV_DIM

typedef __bf16 bf16_t;
typedef __bf16 bf16x8 __attribute__((ext_vector_type(8)));
typedef __bf16 bf16x4 __attribute__((ext_vector_type(4)));
typedef float f32x4 __attribute__((ext_vector_type(4)));

__device__ __forceinline__ f32x4 mfma16x16x32(bf16x8 a, bf16x8 b, f32x4 c) {
    return __builtin_amdgcn_mfma_f32_16x16x32_bf16(a, b, c, 0, 0, 0);
}

// async global->LDS, 16B per lane. LDS dest = wave-uniform base + lane*16;
// global address may be fully per-lane (scatter side is global).
__device__ __forceinline__ void gload_lds16(const bf16_t* g, bf16_t* l) {
    __builtin_amdgcn_global_load_lds(
        (__attribute__((address_space(1))) uint32_t*)(uintptr_t)g,
        (__attribute__((address_space(3))) uint32_t*)l, 16, 0, 0);
}

// Fused fp32->bf16 convert of all 5 tensors in one launch (8 elems/thread).
#define N_X  (NTOK * H_DIM)     // 8388608
#define N_WQ (H_DIM * H_DIM)    // 4194304
#define N_WK (KV_DIM * H_DIM)   // 1048576
__global__ __launch_bounds__(256) void cvt_all(const float* __restrict__ X,
                                               const float* __restrict__ Wq,
                                               const float* __restrict__ Wk,
                                               const float* __restrict__ Wv,
                                               const float* __restrict__ Wo,
                                               bf16_t* __restrict__ Xb,
                                               bf16_t* __restrict__ Wqb,
                                               bf16_t* __restrict__ Wkb,
                                               bf16_t* __restrict__ Wvb,
                                               bf16_t* __restrict__ Wob) {
    long i = (long)(blockIdx.x * 256 + threadIdx.x) * 8;
    const float* src;
    bf16_t* dst;
    if (i < N_X)                       { src = X;  dst = Xb; }
    else if ((i -= N_X) < N_WQ)        { src = Wq; dst = Wqb; }
    else if ((i -= N_WQ) < N_WK)       { src = Wk; dst = Wkb; }
    else if ((i -= N_WK) < N_WK)       { src = Wv; dst = Wvb; }
    else      { i -= N_WK;               src = Wo; dst = Wob; }
    const float4 a = *(const float4*)(src + i);
    const float4 b = *(const float4*)(src + i + 4);
    bf16x8 o;
    o[0] = (bf16_t)a.x; o[1] = (bf16_t)a.y; o[2] = (bf16_t)a.z; o[3] = (bf16_t)a.w;
    o[4] = (bf16_t)b.x; o[5] = (bf16_t)b.y; o[6] = (bf16_t)b.z; o[7] = (bf16_t)b.w;
    *(bf16x8*)(dst + i) = o;
}

// ---- shared GEMM main loop (m97 structure), used by both GEMM kernels ----
// computes acc[4][4] for this thread's 64x64 wave tile at (m0+wm, n0+wn)
#define GEMM_BODY(A_, W_, K_)                                                  \
    __shared__ alignas(16) bf16_t As[128 * 32];                                \
    __shared__ alignas(16) bf16_t Bs[128 * 32];                                \
    const int tid  = threadIdx.x;                                              \
    const int wave = tid >> 6;                                                 \
    const int lane = tid & 63;                                                 \
    const int col  = lane & 15;                                                \
    const int quad = lane >> 4;                                                \
    const int m0 = blockIdx.y * 128;                                           \
    const int n0 = blockIdx.x * 128;                                           \
    const int wm = (wave >> 1) * 64;                                           \
    const int wn = (wave & 1) * 64;                                            \
    const int r0 = tid >> 2;                                                   \
    const int kk = (tid & 3) * 8;                                              \
    const bf16_t* a0 = (A_) + (size_t)(m0 + r0) * (K_) + kk;                   \
    const bf16_t* a1 = a0 + (size_t)64 * (K_);                                 \
    const bf16_t* b0 = (W_) + (size_t)(n0 + r0) * (K_) + kk;                   \
    const bf16_t* b1 = b0 + (size_t)64 * (K_);                                 \
    bf16_t* lA0 = As + tid * 8;                                                \
    bf16_t* lA1 = As + 2048 + tid * 8;                                         \
    bf16_t* lB0 = Bs + tid * 8;                                                \
    bf16_t* lB1 = Bs + 2048 + tid * 8;                                         \
    f32x4 acc[4][4];                                                           \
    _Pragma("unroll") for (int mi = 0; mi < 4; ++mi)                           \
        _Pragma("unroll") for (int ni = 0; ni < 4; ++ni)                       \
            acc[mi][ni] = (f32x4){0.f, 0.f, 0.f, 0.f};                         \
    for (int k0 = 0; k0 < (K_); k0 += 32) {                                    \
        __syncthreads();                                                       \
        gload_lds16(a0 + k0, lA0);                                             \
        gload_lds16(a1 + k0, lA1);                                             \
        gload_lds16(b0 + k0, lB0);                                             \
        gload_lds16(b1 + k0, lB1);                                             \
        __syncthreads();                                                       \
        bf16x8 av[4], bv[4];                                                   \
        _Pragma("unroll") for (int i = 0; i < 4; ++i) {                        \
            av[i] = *(const bf16x8*)(As + (wm + i * 16 + col) * 32 + quad * 8);\
            bv[i] = *(const bf16x8*)(Bs + (wn + i * 16 + col) * 32 + quad * 8);\
        }                                                                      \
        _Pragma("unroll") for (int mi = 0; mi < 4; ++mi)                       \
            _Pragma("unroll") for (int ni = 0; ni < 4; ++ni)                   \
                acc[mi][ni] = mfma16x16x32(av[mi], bv[ni], acc[mi][ni]);       \
    }

// Fused QKV projection: C row-major views into qbuf [M][2048] (n<2048),
// kbuf [M][512] (2048<=n<2560), and V^T layout [b][kvh*128+d][s] (n>=2560).
__global__ __launch_bounds__(256) void gemm_qkv(const bf16_t* __restrict__ A,
                                                const bf16_t* __restrict__ W,
                                                bf16_t* __restrict__ qbuf,
                                                bf16_t* __restrict__ kbuf,
                                                bf16_t* __restrict__ vtbuf) {
    GEMM_BODY(A, W, H_DIM)
    const int ng = n0 + wn;   // 64-aligned; q/k/v boundaries are 64-aligned
    if (ng < H_DIM) {
#pragma unroll
        for (int mi = 0; mi < 4; ++mi)
#pragma unroll
            for (int ni = 0; ni < 4; ++ni)
#pragma unroll
                for (int r = 0; r < 4; ++r)
                    qbuf[(size_t)(m0 + wm + mi * 16 + quad * 4 + r) * H_DIM +
                         ng + ni * 16 + col] = (bf16_t)acc[mi][ni][r];
    } else if (ng < H_DIM + KV_DIM) {
#pragma unroll
        for (int mi = 0; mi < 4; ++mi)
#pragma unroll
            for (int ni = 0; ni < 4; ++ni)
#pragma unroll
                for (int r = 0; r < 4; ++r)
                    kbuf[(size_t)(m0 + wm + mi * 16 + quad * 4 + r) * KV_DIM +
                         ng - H_DIM + ni * 16 + col] = (bf16_t)acc[mi][ni][r];
    } else {
#pragma unroll
        for (int mi = 0; mi < 4; ++mi) {
            const int m = m0 + wm + mi * 16 + quad * 4;
#pragma unroll
            for (int ni = 0; ni < 4; ++ni) {
                const int nv = ng - (H_DIM + KV_DIM) + ni * 16 + col;
                const size_t off =
                    ((size_t)(m >> 11) * KV_DIM + nv) * S_LEN + (m & (S_LEN - 1));
                bf16x4 o;
#pragma unroll
                for (int r = 0; r < 4; ++r) o[r] = (bf16_t)acc[mi][ni][r];
                *(bf16x4*)(vtbuf + off) = o;
            }
        }
    }
}

// O projection: fp32 output.
__global__ __launch_bounds__(256) void gemm_out(const bf16_t* __restrict__ A,
                                                const bf16_t* __restrict__ W,
                                                float* __restrict__ C) {
    GEMM_BODY(A, W, H_DIM)
#pragma unroll
    for (int mi = 0; mi < 4; ++mi)
#pragma unroll
        for (int ni = 0; ni < 4; ++ni)
#pragma unroll
            for (int r = 0; r < 4; ++r)
                C[(size_t)(m0 + wm + mi * 16 + quad * 4 + r) * H_DIM +
                  n0 + wn + ni * 16 + col] = (float)acc[mi][ni][r];
}

// In-place RoPE on Q [NTOK][2048] (16 heads) and K [NTOK][512] (4 heads).
__global__ __launch_bounds__(256) void rope_inplace(bf16_t* __restrict__ Qb,
                                                    bf16_t* __restrict__ Kb,
                                                    const float* __restrict__ cosb,
                                                    const float* __restrict__ sinb) {
    const int idx  = blockIdx.x * 256 + threadIdx.x;
    const int d    = idx & 63;
    const int rem  = idx >> 6;
    const int head = rem % 20;
    const int row  = rem / 20;
    if (row >= NTOK) return;
    const int s = row & (S_LEN - 1);
    const float c0 = cosb[s * HEAD_DIM + d];
    const float s0 = sinb[s * HEAD_DIM + d];
    const float c1 = cosb[s * HEAD_DIM + 64 + d];
    const float s1 = sinb[s * HEAD_DIM + 64 + d];
    bf16_t* base = (head < NHEADS)
        ? Qb + (size_t)row * H_DIM + head * HEAD_DIM
        : Kb + (size_t)row * KV_DIM + (head - NHEADS) * HEAD_DIM;
    const float lo = (float)base[d];
    const float hi = (float)base[d + 64];
    base[d]      = (bf16_t)(lo * c0 - hi * s0);
    base[d + 64] = (bf16_t)(hi * c1 + lo * s1);
}

#define NEG_BIG (-1e30f)
#define TJ 64   // kv tile width

// Flash attention, causal, transposed-score form. Block = (pair p, kvh, b);
// 4 waves = 4 GQA heads; q-tiles {p, 127-p} sequential -> 33 x 64-wide
// kv-steps per block (balanced). K/V tiles staged into double-buffered LDS
// via global_load_lds with XOR-swizzled *global* source addressing: the DMA
// LDS write is lane-contiguous (conflict-free by construction) and the
// swizzle makes all fragment ds_reads 2-way (free). One barrier per step;
// its vmcnt(0) drain is what retires the previous step's async staging.
// Output written in place into Q (each (tile,head) region owned by 1 wave).
__global__ __launch_bounds__(256, 2) void attn_fwd(bf16_t* __restrict__ Q,
                                                   const bf16_t* __restrict__ Kb,
                                                   const bf16_t* __restrict__ Vt) {
    const int p   = blockIdx.x;        // 0..63
    const int kvh = blockIdx.y;
    const int b   = blockIdx.z;
    const int tid  = threadIdx.x;
    const int wave = tid >> 6;
    const int lane = tid & 63;
    const int col  = lane & 15;
    const int quad = lane >> 4;
    const int h = kvh * 4 + wave;
    const int swz = col & 7;           // read-side swizzle key

    // chunk-swizzled tiles: slot(j,c) = j*16 + (c^(j&7)) for K [64j][16c],
    // slot(d,cj) = d*8 + (cj^(d&7)) for V^T [128d][8cj]; elem addr = slot*8.
    __shared__ alignas(16) bf16_t Ks[2][TJ * HEAD_DIM];    // 16 KB each
    __shared__ alignas(16) bf16_t Vs[2][HEAD_DIM * TJ];    // 16 KB each
    __shared__ alignas(16) bf16_t Pt[4][16][72];           // [wave][q][j] pad72

    const bf16_t* kbase = Kb + (size_t)(b * S_LEN) * KV_DIM + kvh * HEAD_DIM;
    const bf16_t* vtb   = Vt + (size_t)(b * KVHEADS + kvh) * HEAD_DIM * S_LEN;
    const float scale = 0.08838834764831845f;  // 1/sqrt(128)

    // per-lane global element offsets for the 4 K + 4 V staging DMAs
    int kgoff[4], vgoff[4];
#pragma unroll
    for (int i = 0; i < 4; ++i) {
        const int s = wave * 256 + i * 64 + lane;
        const int j = s >> 4, c = (s & 15) ^ (j & 7);
        kgoff[i] = j * KV_DIM + c * 8;
        const int d = s >> 3, cj = (s & 7) ^ (d & 7);
        vgoff[i] = d * S_LEN + cj * 8;
    }
    auto stage = [&](int buf, int j0) {
        const bf16_t* kb = kbase + (size_t)j0 * KV_DIM;
        const bf16_t* vb = vtb + j0;
#pragma unroll
        for (int i = 0; i < 4; ++i) {
            bf16_t* lk = &Ks[buf][(wave * 256 + i * 64) * 8];
            bf16_t* lv = &Vs[buf][(wave * 256 + i * 64) * 8];
            gload_lds16(kb + kgoff[i], lk);
            gload_lds16(vb + vgoff[i], lv);
        }
    };

#pragma unroll 1
    for (int half = 0; half < 2; ++half) {
        const int qt = half ? (127 - p) : p;
        const int q0 = qt * 16;
        const int nsteps = (qt >> 2) + 1;

        __syncthreads();          // prior half's buffer reads complete
        stage(0, 0);

        bf16x8 qf[4];
        {
            const bf16_t* qp = Q + (size_t)(b * S_LEN + q0 + col) * H_DIM +
                               h * HEAD_DIM + quad * 8;
#pragma unroll
            for (int t = 0; t < 4; ++t) qf[t] = *(const bf16x8*)(qp + t * 32);
        }
        f32x4 Oacc[8];
#pragma unroll
        for (int dt = 0; dt < 8; ++dt) Oacc[dt] = (f32x4){0.f, 0.f, 0.f, 0.f};
        float m_i = NEG_BIG, l_i = 0.f;

        for (int jt = 0; jt < nsteps; ++jt) {
            const int cur = jt & 1;
            const bool last = (jt == nsteps - 1);
            __syncthreads();   // vmcnt(0) drain: buf cur staged; prev reads done
            if (!last) stage(cur ^ 1, (jt + 1) * TJ);

            // S^T(64x16) = K . Q^T
            f32x4 sc[4];
#pragma unroll
            for (int jc = 0; jc < 4; ++jc) sc[jc] = (f32x4){0.f, 0.f, 0.f, 0.f};
#pragma unroll
            for (int t = 0; t < 4; ++t)
#pragma unroll
                for (int jc = 0; jc < 4; ++jc) {
                    const int slot = ((jc * 16 + col) << 4) + ((4 * t + quad) ^ swz);
                    const bf16x8 kf = *(const bf16x8*)(&Ks[cur][slot << 3]);
                    sc[jc] = mfma16x16x32(kf, qf[t], sc[jc]);
                }

            const int j0 = jt * TJ;
            const int q = q0 + col;
#pragma unroll
            for (int jc = 0; jc < 4; ++jc)
#pragma unroll
                for (int r = 0; r < 4; ++r) {
                    float v = sc[jc][r] * scale;
                    if (last) {
                        const int j = j0 + jc * 16 + quad * 4 + r;
                        v = (j <= q) ? v : NEG_BIG;
                    }
                    sc[jc][r] = v;
                }
            // column (q) max over 16 elems: in-lane tree + 2 butterflies
            float mx = sc[0][0];
#pragma unroll
            for (int jc = 0; jc < 4; ++jc)
#pragma unroll
                for (int r = 0; r < 4; ++r) mx = fmaxf(mx, sc[jc][r]);
            mx = fmaxf(mx, __shfl_xor(mx, 16));
            mx = fmaxf(mx, __shfl_xor(mx, 32));
            const float mn = fmaxf(m_i, mx);
            const float alpha = __expf(m_i - mn);
            m_i = mn;
            float sum = 0.f;
            float pe[4][4];
#pragma unroll
            for (int jc = 0; jc < 4; ++jc)
#pragma unroll
                for (int r = 0; r < 4; ++r) {
                    pe[jc][r] = __expf(sc[jc][r] - mn);
                    sum += pe[jc][r];
                }
            sum += __shfl_xor(sum, 16);
            sum += __shfl_xor(sum, 32);
            l_i = l_i * alpha + sum;
            // write P^T as [q][j]
#pragma unroll
            for (int jc = 0; jc < 4; ++jc) {
                bf16x4 w;
#pragma unroll
                for (int r = 0; r < 4; ++r) w[r] = (bf16_t)pe[jc][r];
                *(bf16x4*)(&Pt[wave][col][jc * 16 + quad * 4]) = w;
            }
            // broadcast alpha (per q=col) to O rows (q=quad*4+r), rescale O
            float ar[4];
#pragma unroll
            for (int r = 0; r < 4; ++r) ar[r] = __shfl(alpha, quad * 4 + r, 16);
#pragma unroll
            for (int dt = 0; dt < 8; ++dt)
#pragma unroll
                for (int r = 0; r < 4; ++r) Oacc[dt][r] *= ar[r];

            asm volatile("s_waitcnt lgkmcnt(0)" ::: "memory");  // P visible
            const bf16x8 aP0 = *(const bf16x8*)(&Pt[wave][col][quad * 8]);
            const bf16x8 aP1 = *(const bf16x8*)(&Pt[wave][col][32 + quad * 8]);
#pragma unroll
            for (int dt = 0; dt < 8; ++dt) {
                const int d = dt * 16 + col;
                const int s0 = (d << 3) + (quad ^ swz);
                const int s1 = (d << 3) + ((quad + 4) ^ swz);
                const bf16x8 vf0 = *(const bf16x8*)(&Vs[cur][s0 << 3]);
                const bf16x8 vf1 = *(const bf16x8*)(&Vs[cur][s1 << 3]);
                Oacc[dt] = mfma16x16x32(aP1, vf1,
                           mfma16x16x32(aP0, vf0, Oacc[dt]));
            }
        }

        // normalize (broadcast l to O rows) and store in place
        float lr[4];
#pragma unroll
        for (int r = 0; r < 4; ++r) lr[r] = __shfl(l_i, quad * 4 + r, 16);
#pragma unroll
        for (int r = 0; r < 4; ++r) {
            const float inv = 1.0f / lr[r];
            const size_t rowoff =
                (size_t)(b * S_LEN + q0 + quad * 4 + r) * H_DIM + h * HEAD_DIM;
#pragma unroll
            for (int dt = 0; dt < 8; ++dt)
                Q[rowoff + dt * 16 + col] = (bf16_t)(Oacc[dt][r] * inv);
        }
    }
}

extern "C" void kernel_launch(void* const* d_in, const int* in_sizes, int n_in,
                              void* d_out, int out_size, void* d_ws, size_t ws_size,
                              hipStream_t stream) {
    const float* X    = (const float*)d_in[0];
    const float* cosb = (const float*)d_in[1];
    const float* sinb = (const float*)d_in[2];
    const float* Wq   = (const float*)d_in[3];
    const float* Wk   = (const float*)d_in[4];
    const float* Wv   = (const float*)d_in[5];
    const float* Wo   = (const float*)d_in[6];
    float* out = (float*)d_out;

    // ws (bf16): Xb 16MB | Wqkv 12MB (q 8, k 2, v 2 contiguous) | Wob 8MB |
    //            Q 16MB | K 4MB | V^T 4MB
    char* ws = (char*)d_ws;
    bf16_t* Xb    = (bf16_t*)(ws);
    bf16_t* Wqkvb = (bf16_t*)(ws + (16u << 20));
    bf16_t* Wkb   = (bf16_t*)(ws + (24u << 20));
    bf16_t* Wvb   = (bf16_t*)(ws + (26u << 20));
    bf16_t* Wob   = (bf16_t*)(ws + (28u << 20));
    bf16_t* qbuf  = (bf16_t*)(ws + (36u << 20));
    bf16_t* kbuf  = (bf16_t*)(ws + (52u << 20));
    bf16_t* vtbuf = (bf16_t*)(ws + (56u << 20));

    dim3 blk(256, 1, 1);
    const int ncvt = N_X + 2 * N_WQ + 2 * N_WK;   // /2048 = 9216 blocks
    cvt_all<<<dim3(ncvt / 2048, 1, 1), blk, 0, stream>>>(
        X, Wq, Wk, Wv, Wo, Xb, Wqkvb, Wkb, Wvb, Wob);

    gemm_qkv<<<dim3(NQKV / 128, NTOK / 128), blk, 0, stream>>>(
        Xb, Wqkvb, qbuf, kbuf, vtbuf);
    rope_inplace<<<dim3((NTOK * 20 * 64) / 256), blk, 0, stream>>>(
        qbuf, kbuf, cosb, sinb);
    attn_fwd<<<dim3(64, KVHEADS, 2), blk, 0, stream>>>(qbuf, kbuf, vtbuf);
    gemm_out<<<dim3(H_DIM / 128, NTOK / 128), blk, 0, stream>>>(qbuf, Wob, out);

    (void)in_sizes; (void)n_in; (void)out_size; (void)ws_size;
}